// Round 6
// baseline (226.147 us; speedup 1.0000x reference)
//
#include <hip/hip_runtime.h>

// VQ-VAE vector quantizer, MI355X (gfx950).
// Round 11:
//  - LOSS FIX: round-10 fused loss summed bestv = ||c||^2 - 2 z.c, missing
//    ||z||^2 (absmax 1.2156 = the loss error). Now each row contributes
//    vrow = Sz(row) + bestv (Sz accumulated fp64 during A-load, free), and
//    bv2a/bvfa store the SAME vrow so fixup deltas cancel exactly.
//  - argmin: 32 pts/wave + in-block code-half split. Block = 128 pts x 512
//    thr = 8 waves (4 point-groups x 2 code-halves). Halves chip LDS-read
//    traffic (dominant 98k -> 49k cyc/CU) while keeping 4 waves/SIMD
//    (launch_bounds(512,4) -> VGPR <= 128; est ~124). Two independent MFMA
//    acc chains. Cross-half top-3 merge in-block (r9 code), epilogue fusion
//    (scatter + loss + flags) kept.
//
// d_out scratch (bytes, all consumed before small_gather / overwritten later):
//   [0,524288) cbh_perm | [524288,786432) bv2a | [786432,1048576) bvfa
//   [1048576,1572864) ull minkey scratch | [1572864,1835008) flagf
// d_ws: [0,2048) double loss_slots[256]; [2048,2052) cnt2; [2052,2056) cntf;
//       [4096,8192) float Bf[1024]; [8192,270336) uint flag2 (n | seck<<16)

#define N_PTS    65536
#define K_CODES  1024
#define DIM      256
#define MARGIN   1.5e-4f
#define WSKIP    4096

#define OUT_VALS  16777216
#define OUT_CODES 65536

typedef __attribute__((ext_vector_type(8))) short short8v;
typedef __attribute__((ext_vector_type(8))) _Float16 half8v;
typedef __attribute__((ext_vector_type(4))) float float4v;

// perm index (in shorts) for codebook element (r=code, k=dim):
// chunk = ((r>>4)*8 + (k>>5))*4 + ((k>>3)&3); idx = chunk*128 + (r&15)*8 + (k&7)
__device__ __forceinline__ int perm_idx(int r, int k) {
  return ((((r >> 4) * 8 + (k >> 5)) * 4 + ((k >> 3) & 3)) * 128) + (r & 15) * 8 + (k & 7);
}

__device__ __forceinline__ short f2h_bits(float x) {
  union { _Float16 h; short s; } u;
  u.h = (_Float16)x;              // v_cvt_f16_f32, RTE
  return u.s;
}

__device__ __forceinline__ void gload16(const void* g, void* l) {
  __builtin_amdgcn_global_load_lds(
      (const __attribute__((address_space(1))) unsigned*)g,
      (__attribute__((address_space(3))) unsigned*)l, 16, 0, 0);
}

// one wave per code row: Bf[r] = fl32(fp64 sum sq of ORIGINAL cb); emit
// fp16(1024*cb) in B-fragment-permuted order. Also init ws header + scratch.
__global__ void prep_cb_kernel(const float* __restrict__ cb,
                               short* __restrict__ cbh_perm,
                               float* __restrict__ Bf,
                               unsigned long long* __restrict__ scratch,
                               unsigned long long* __restrict__ ws0) {
  const int gid = blockIdx.x * 256 + threadIdx.x;
  scratch[gid] = ~0ull;                       // 65536 minkeys
  if (gid < 512) ws0[gid] = 0ull;             // loss_slots + cnt2/cntf
  int r    = blockIdx.x * 4 + (threadIdx.x >> 6);
  int lane = threadIdx.x & 63;
  const float4 v = *(const float4*)(cb + (size_t)r * DIM + lane * 4);
  double s = (double)v.x * v.x + (double)v.y * v.y
           + (double)v.z * v.z + (double)v.w * v.w;
#pragma unroll
  for (int off = 32; off > 0; off >>= 1) s += __shfl_down(s, off);
  if (lane == 0) Bf[r] = (float)s;
  short4 h = make_short4(f2h_bits(v.x * 1024.0f), f2h_bits(v.y * 1024.0f),
                         f2h_bits(v.z * 1024.0f), f2h_bits(v.w * 1024.0f));
  *(short4*)(cbh_perm + perm_idx(r, lane * 4)) = h;   // 8B aligned
}

// 512 blocks x 512 thr (8 waves). Block: 128 points x all 1024 codes.
// Wave (wp = w>>1, h = w&1): points [m0 + wp*32, +32), codes [h*512, +512).
// 16-code tiles double-buffered per half via global_load_lds.
__global__ __launch_bounds__(512, 4) void argmin_mfma_kernel(
    const float* __restrict__ z, const float* __restrict__ cb,
    const short* __restrict__ cbh_perm,
    const float* __restrict__ Bf, float* __restrict__ outq,
    float* __restrict__ codes_out,
    int* __restrict__ cnt2, int* __restrict__ cntf,
    unsigned* __restrict__ flag2, int* __restrict__ flagf,
    float* __restrict__ bv2a, float* __restrict__ bvfa,
    double* __restrict__ loss_slots) {
  __shared__ __align__(16) short lbuf[2][2][4096];   // [half][buf][16c x 256d]
  __shared__ float mv1[128][2], mv2[128][2], mv3[128][2];
  __shared__ int   mk1[128][2], mk2[128][2];
  __shared__ float mz[128];
  __shared__ int   scodes[128];
  __shared__ double wls[2];
  const int t    = threadIdx.x;
  const int w    = t >> 6;
  const int l    = t & 63;
  const int quad = l >> 4;
  const int lr   = l & 15;
  const int wp   = w >> 1;          // point group 0..3
  const int h    = w & 1;           // code half
  const int m0   = blockIdx.x * 128;
  const int pbase = m0 + wp * 32;

  // stage tile 0 of this wave's half early (hides under A-load/convert).
  // wave covers bytes [wp*2048, +2048) of the 8192-byte tile.
  {
    const char* src = (const char*)cbh_perm + (size_t)(h * 32) * 8192 + wp * 2048;
    char* dst = (char*)&lbuf[h][0][0] + wp * 2048;
    gload16(src + l * 16, dst + l * 16);
    gload16(src + 1024 + l * 16, dst + 1024 + l * 16);
  }

  // A-fragments for 2 x 16 rows + fp64 row sums of squares.
  half8v ah[2][8];
  float Szrow[2];
#pragma unroll
  for (int a = 0; a < 2; ++a) {
    const float* zrow = z + (size_t)(pbase + a * 16 + lr) * DIM;
    double zs = 0.0;
#pragma unroll
    for (int q = 0; q < 8; ++q) {
      float4 p0 = *(const float4*)(zrow + q * 32 + quad * 8);
      float4 p1 = *(const float4*)(zrow + q * 32 + quad * 8 + 4);
      zs = fma((double)p0.x, (double)p0.x, zs);
      zs = fma((double)p0.y, (double)p0.y, zs);
      zs = fma((double)p0.z, (double)p0.z, zs);
      zs = fma((double)p0.w, (double)p0.w, zs);
      zs = fma((double)p1.x, (double)p1.x, zs);
      zs = fma((double)p1.y, (double)p1.y, zs);
      zs = fma((double)p1.z, (double)p1.z, zs);
      zs = fma((double)p1.w, (double)p1.w, zs);
      half8v hh;
      hh[0] = (_Float16)p0.x; hh[1] = (_Float16)p0.y;
      hh[2] = (_Float16)p0.z; hh[3] = (_Float16)p0.w;
      hh[4] = (_Float16)p1.x; hh[5] = (_Float16)p1.y;
      hh[6] = (_Float16)p1.z; hh[7] = (_Float16)p1.w;
      ah[a][q] = hh;
    }
    zs += __shfl_xor(zs, 16);      // sum the 4 quads of row a*16 + lr
    zs += __shfl_xor(zs, 32);
    Szrow[a] = (float)zs;          // lane l: ||z[pbase + a*16 + (l&15)]||^2
  }

  // top-3 per slot s = a*4 + r  (row = a*16 + quad*4 + r in C)
  float bv[8], sv[8], tv[8]; int bk[8], sk[8];
#pragma unroll
  for (int s = 0; s < 8; ++s) {
    bv[s] = 3.0e38f; sv[s] = 3.0e38f; tv[s] = 3.0e38f; bk[s] = 0; sk[s] = 0;
  }

  __syncthreads();          // tile 0 resident (full drain)
  int cur = 0;
  for (int it = 0; it < 32; ++it) {
    if (it < 31) {          // prefetch next tile of this half
      const char* src = (const char*)cbh_perm + (size_t)(h * 32 + it + 1) * 8192 + wp * 2048;
      char* dst = (char*)&lbuf[h][cur ^ 1][0] + wp * 2048;
      gload16(src + l * 16, dst + l * 16);
      gload16(src + 1024 + l * 16, dst + 1024 + l * 16);
    }
    const short* bb = &lbuf[h][cur][0];
    float4v acc0 = {0.f, 0.f, 0.f, 0.f};
    float4v acc1 = {0.f, 0.f, 0.f, 0.f};
#pragma unroll
    for (int q = 0; q < 8; ++q) {
      half8v b = *(const half8v*)(bb + q * 512 + quad * 128 + lr * 8);
      acc0 = __builtin_amdgcn_mfma_f32_16x16x32_f16(ah[0][q], b, acc0, 0, 0, 0);
      acc1 = __builtin_amdgcn_mfma_f32_16x16x32_f16(ah[1][q], b, acc1, 0, 0, 0);
    }
    const int k = (h * 32 + it) * 16 + lr;     // this lane's code (C col = lr)
    const float bkf = Bf[k];
#pragma unroll
    for (int a = 0; a < 2; ++a) {
#pragma unroll
      for (int r = 0; r < 4; ++r) {
        const int s = a * 4 + r;
        float v = fmaf(-0.001953125f, a ? acc1[r] : acc0[r], bkf);  // -2/1024
        bool lt1 = v < bv[s];
        bool lt2 = v < sv[s];
        tv[s] = fminf(fmaxf(v, sv[s]), tv[s]);   // med3
        sv[s] = fminf(fmaxf(v, bv[s]), sv[s]);   // med3
        bv[s] = fminf(v, bv[s]);
        sk[s] = lt1 ? bk[s] : (lt2 ? k : sk[s]);
        bk[s] = lt1 ? k : bk[s];
      }
    }
    __syncthreads();        // drains vmcnt: next tile landed; readers done
    cur ^= 1;
  }

  // top-3 merge across the 16 col-lanes of each quad (butterfly)
#pragma unroll
  for (int mask = 1; mask < 16; mask <<= 1) {
#pragma unroll
    for (int s = 0; s < 8; ++s) {
      float ov  = __shfl_xor(bv[s], mask);
      float os  = __shfl_xor(sv[s], mask);
      float ot  = __shfl_xor(tv[s], mask);
      int   ok  = __shfl_xor(bk[s], mask);
      int   osk = __shfl_xor(sk[s], mask);
      bool win = (ov < bv[s]) || (ov == bv[s] && ok < bk[s]);
      float a1 = win ? ov : bv[s], a2 = win ? os : sv[s], a3 = win ? ot : tv[s];
      int   a1k = win ? ok : bk[s], a2k = win ? osk : sk[s];
      float b1 = win ? bv[s] : ov, b2 = win ? sv[s] : os;
      int   b1k = win ? bk[s] : ok;
      bool s2 = (a2 < b1) || (a2 == b1 && a2k < b1k);
      bv[s] = a1; bk[s] = a1k;
      sv[s] = s2 ? a2 : b1; sk[s] = s2 ? a2k : b1k;
      tv[s] = s2 ? fminf(a3, b1) : fminf(a2, b2);
    }
  }

  // publish per-(point, half) triples + row ||z||^2
  if (lr == 0) {
#pragma unroll
    for (int a = 0; a < 2; ++a)
#pragma unroll
      for (int r = 0; r < 4; ++r) {
        int s  = a * 4 + r;
        int pt = wp * 32 + a * 16 + quad * 4 + r;
        mv1[pt][h] = bv[s]; mv2[pt][h] = sv[s]; mv3[pt][h] = tv[s];
        mk1[pt][h] = bk[s]; mk2[pt][h] = sk[s];
      }
  }
  if (h == 0 && quad == 0) {
#pragma unroll
    for (int a = 0; a < 2; ++a)
      mz[wp * 32 + a * 16 + lr] = Szrow[a];
  }
  __syncthreads();

  // merge halves per point (t < 128); flags + codes + loss contribution
  double ls = 0.0;
  if (t < 128) {
    float a1 = mv1[t][0], a2 = mv2[t][0], a3 = mv3[t][0];
    int   a1k = mk1[t][0], a2k = mk2[t][0];
    float c1 = mv1[t][1], c2 = mv2[t][1], c3 = mv3[t][1];
    int   c1k = mk1[t][1], c2k = mk2[t][1];
    bool win = (c1 < a1) || (c1 == a1 && c1k < a1k);
    float x1 = win ? c1 : a1, x2 = win ? c2 : a2, x3 = win ? c3 : a3;
    int   x1k = win ? c1k : a1k, x2k = win ? c2k : a2k;
    float y1 = win ? a1 : c1, y2 = win ? a2 : c2;
    int   y1k = win ? a1k : c1k;
    bool s2 = (x2 < y1) || (x2 == y1 && x2k < y1k);
    float f2v = s2 ? x2 : y1; int f2k = s2 ? x2k : y1k;
    float f3v = s2 ? fminf(x3, y1) : fminf(x2, y2);
    int n = m0 + t;
    codes_out[n] = (float)x1k;
    scodes[t] = x1k;
    float vrow = mz[t] + x1;        // Sz + approx best: the loss contribution
    ls = (double)vrow;
    if (f3v - x1 < MARGIN) {
      int pos = atomicAdd(cntf, 1);
      flagf[pos] = n; bvfa[pos] = vrow;
    } else if (f2v - x1 < MARGIN) {
      int pos = atomicAdd(cnt2, 1);
      flag2[pos] = (unsigned)n | ((unsigned)f2k << 16);
      bv2a[pos] = vrow;
    }
  }
#pragma unroll
  for (int off = 32; off > 0; off >>= 1) ls += __shfl_down(ls, off);
  if (l == 0 && w < 2) wls[w] = ls;
  __syncthreads();

  // fused quantized scatter (rows < WSKIP deferred: they overlap scratch)
  if (m0 >= WSKIP) {
#pragma unroll
    for (int i = 0; i < 16; ++i) {
      int row = i * 8 + w;
      int c = scodes[row];
      *(float4*)(outq + (size_t)(m0 + row) * DIM + l * 4) =
          *(const float4*)(cb + (size_t)c * DIM + l * 4);
    }
  }
  if (t == 0)
    atomicAdd(&loss_slots[blockIdx.x & 255], wls[0] + wls[1]);
}

// Pair fixup: one wave per flagged row; half-wave per candidate code.
// Exact emulation: v = fl32(fl32(Sfl + Bf[k]) - 2*fl32(dot64)); tie -> lower k.
// Loss delta = v_exact(min) - bv2a[i] (bv2a = Sz + approx bv, the value added).
__global__ __launch_bounds__(256) void fixup_pair_kernel(
    const float* __restrict__ z, const float* __restrict__ cb,
    const float* __restrict__ Bf, const unsigned* __restrict__ flag2,
    const int* __restrict__ cnt2, const float* __restrict__ bv2a,
    float* __restrict__ codes_out, float* __restrict__ outq,
    double* __restrict__ loss_slots) {
  const int t   = threadIdx.x;
  const int l   = t & 63;
  const int h   = l >> 5;          // 0 -> bestk, 1 -> seck
  const int sub = l & 31;          // dims sub*8 .. sub*8+7
  const int wid = blockIdx.x * 4 + (t >> 6);
  const int nw  = gridDim.x * 4;
  const int cnt = *cnt2;
  for (int i = wid; i < cnt; i += nw) {
    const unsigned rec = flag2[i];
    const int n  = rec & 0xFFFF;
    const int k2 = rec >> 16;
    const int k1 = (int)codes_out[n];
    const int k  = h ? k2 : k1;
    const float* zr = z + (size_t)n * DIM + sub * 8;
    const float* cr = cb + (size_t)k * DIM + sub * 8;
    const float4 za = *(const float4*)(zr);
    const float4 zb = *(const float4*)(zr + 4);
    const float4 ca = *(const float4*)(cr);
    const float4 cv = *(const float4*)(cr + 4);
    double s = (double)za.x*za.x + (double)za.y*za.y + (double)za.z*za.z + (double)za.w*za.w
             + (double)zb.x*zb.x + (double)zb.y*zb.y + (double)zb.z*zb.z + (double)zb.w*zb.w;
    double d = (double)za.x*ca.x + (double)za.y*ca.y + (double)za.z*ca.z + (double)za.w*ca.w
             + (double)zb.x*cv.x + (double)zb.y*cv.y + (double)zb.z*cv.z + (double)zb.w*cv.w;
#pragma unroll
    for (int m = 1; m < 32; m <<= 1) {
      s += __shfl_xor(s, m);
      d += __shfl_xor(d, m);
    }
    const float Sfl = (float)s;
    const float T1  = Sfl + Bf[k];
    const float v   = T1 - 2.0f * (float)d;
    const float vo  = __shfl_xor(v, 32);
    const int   ko  = __shfl_xor(k, 32);
    const bool keep = (v < vo) || (v == vo && k < ko);
    const float vmin = keep ? v : vo;
    const int   kf   = keep ? k : ko;       // consistent across both halves
    if (l == 0) {
      codes_out[n] = (float)kf;
      atomicAdd(&loss_slots[n & 255], (double)(vmin - bv2a[i]));
    }
    if (kf != k1 && n >= WSKIP)
      *(float4*)(outq + (size_t)n * DIM + l * 4) =
          *(const float4*)(cb + (size_t)kf * DIM + l * 4);
  }
}

// Full rescan for rows with 3+ candidates inside MARGIN (expected ~tens).
// 4 blocks per row; cross-block merge via atomicMin on (f32-bits<<32 | k).
__global__ __launch_bounds__(256) void fixup_full_kernel(
    const float* __restrict__ z, const float* __restrict__ cb,
    const float* __restrict__ Bf, const int* __restrict__ flagf,
    const int* __restrict__ cntf, unsigned long long* __restrict__ scratch) {
  __shared__ float vred[4];
  __shared__ int   kred[4];
  const int t = threadIdx.x;
  const int w = t >> 6;
  const int l = t & 63;
  const int cnt = *cntf;
  for (int ib = blockIdx.x; (ib >> 2) < cnt; ib += gridDim.x) {
    const int i = ib >> 2, q = ib & 3;
    const int n = flagf[i];
    const float4 zv = *(const float4*)(z + (size_t)n * DIM + l * 4);
    double s = (double)zv.x*zv.x + (double)zv.y*zv.y
             + (double)zv.z*zv.z + (double)zv.w*zv.w;
#pragma unroll
    for (int off = 32; off > 0; off >>= 1) s += __shfl_xor(s, off);
    const float Sfl = (float)s;
    float bvv = 3.0e38f; int bkk = 0;
    const int kbase = q * 256 + w * 64;
#pragma unroll 4
    for (int k0 = 0; k0 < 64; ++k0) {
      const int k = kbase + k0;
      const float4 cv = *(const float4*)(cb + (size_t)k * DIM + l * 4);
      double d = (double)zv.x*cv.x + (double)zv.y*cv.y
               + (double)zv.z*cv.z + (double)zv.w*cv.w;
#pragma unroll
      for (int off = 32; off > 0; off >>= 1) d += __shfl_xor(d, off);
      float T1 = Sfl + Bf[k];
      float v  = T1 - 2.0f * (float)d;
      if (v < bvv) { bvv = v; bkk = k; }   // ascending k -> lowest on tie
    }
    __syncthreads();
    if (l == 0) { vred[w] = bvv; kred[w] = bkk; }
    __syncthreads();
    if (t == 0) {
      float fv = vred[0]; int fk = kred[0];
#pragma unroll
      for (int j = 1; j < 4; ++j) {
        float v2 = vred[j]; int kk = kred[j];
        if (v2 < fv || (v2 == fv && kk < fk)) { fv = v2; fk = kk; }
      }
      unsigned long long key =
          ((unsigned long long)__float_as_uint(fv) << 32) | (unsigned)fk;
      atomicMin(&scratch[n], key);
    }
  }
}

// Resolve full rows: wave per row; codes + loss delta + row rewrite.
__global__ __launch_bounds__(256) void fixup_write_kernel(
    const int* __restrict__ flagf, const int* __restrict__ cntf,
    const unsigned long long* __restrict__ scratch,
    const float* __restrict__ bvfa, const float* __restrict__ cb,
    float* __restrict__ codes_out, float* __restrict__ outq,
    double* __restrict__ loss_slots) {
  const int t = threadIdx.x, l = t & 63;
  const int wid = blockIdx.x * 4 + (t >> 6);
  const int nw  = gridDim.x * 4;
  const int cnt = *cntf;
  for (int i = wid; i < cnt; i += nw) {
    const int n = flagf[i];
    const unsigned long long key = scratch[n];
    const int   fk = (int)(unsigned)(key & 0xFFFFFFFFull);
    const float fv = __uint_as_float((unsigned)(key >> 32));
    const int   k1 = (int)codes_out[n];
    if (l == 0) {
      codes_out[n] = (float)fk;
      atomicAdd(&loss_slots[n & 255], (double)(fv - bvfa[i]));
    }
    if (fk != k1 && n >= WSKIP)
      *(float4*)(outq + (size_t)n * DIM + l * 4) =
          *(const float4*)(cb + (size_t)fk * DIM + l * 4);
  }
}

// Rows [0, WSKIP): scatter cb[codes[n]] after all fixups (scratch now dead).
__global__ void small_gather_kernel(const float* __restrict__ cb,
                                    const float* __restrict__ codes_f,
                                    float* __restrict__ outq) {
  int gid = blockIdx.x * 256 + threadIdx.x;
  int n = gid >> 6, l = gid & 63;
  int c = (int)codes_f[n];
  *(float4*)(outq + (size_t)n * DIM + l * 4) =
      *(const float4*)(cb + (size_t)c * DIM + l * 4);
}

__global__ void finalize_kernel(const double* __restrict__ loss_slots,
                                float* __restrict__ out_loss) {
  const int t = threadIdx.x;          // 256 threads
  double s = loss_slots[t];
#pragma unroll
  for (int off = 32; off > 0; off >>= 1) s += __shfl_down(s, off);
  __shared__ double ws[4];
  if ((t & 63) == 0) ws[t >> 6] = s;
  __syncthreads();
  if (t == 0) {
    double tot = ws[0] + ws[1] + ws[2] + ws[3];
    out_loss[0] = (float)(1.25 * tot / (double)(N_PTS * (size_t)DIM));
  }
}

extern "C" void kernel_launch(void* const* d_in, const int* in_sizes, int n_in,
                              void* d_out, int out_size, void* d_ws, size_t ws_size,
                              hipStream_t stream) {
  const float* z  = (const float*)d_in[0];
  const float* cb = (const float*)d_in[1];
  float* out = (float*)d_out;
  double* loss_slots = (double*)d_ws;
  int*      cnt2  = (int*)((char*)d_ws + 2048);
  int*      cntf  = (int*)((char*)d_ws + 2052);
  float*    Bf    = (float*)((char*)d_ws + 4096);
  unsigned* flag2 = (unsigned*)((char*)d_ws + 8192);
  short* cbh_perm = (short*)d_out;                                   // [0,512K)
  float* bv2a     = (float*)((char*)d_out + 524288);
  float* bvfa     = (float*)((char*)d_out + 786432);
  unsigned long long* scratch = (unsigned long long*)((char*)d_out + 1048576);
  int*   flagf    = (int*)((char*)d_out + 1572864);

  prep_cb_kernel<<<K_CODES / 4, 256, 0, stream>>>(
      cb, cbh_perm, Bf, scratch, (unsigned long long*)d_ws);
  argmin_mfma_kernel<<<N_PTS / 128, 512, 0, stream>>>(
      z, cb, cbh_perm, Bf, out, out + OUT_VALS, cnt2, cntf, flag2, flagf,
      bv2a, bvfa, loss_slots);
  fixup_pair_kernel<<<1024, 256, 0, stream>>>(
      z, cb, Bf, flag2, cnt2, bv2a, out + OUT_VALS, out, loss_slots);
  fixup_full_kernel<<<2048, 256, 0, stream>>>(z, cb, Bf, flagf, cntf, scratch);
  fixup_write_kernel<<<64, 256, 0, stream>>>(
      flagf, cntf, scratch, bvfa, cb, out + OUT_VALS, out, loss_slots);
  small_gather_kernel<<<WSKIP * 64 / 256, 256, 0, stream>>>(
      cb, out + OUT_VALS, out);
  finalize_kernel<<<1, 256, 0, stream>>>(loss_slots, out + OUT_VALS + OUT_CODES);
}

// Round 7
// 217.116 us; speedup vs baseline: 1.0416x; 1.0416x over previous
//
#include <hip/hip_runtime.h>

// VQ-VAE vector quantizer, MI355X (gfx950).
// Round 12: 32 pts/wave done right (r11 spilled: launch_bounds(512,4) pinned
// 64 VGPR vs the 64-VGPR A-frag set alone -> 26MB scratch writes).
//  - r10 structure kept: 256 thr / 4 waves, no code split, dbuf
//    global_load_lds, one barrier/iter. Each wave: TWO 16-row A-groups
//    (ah[2][8]=64 VGPR), 8 top-3 slots, acc0/acc1 share each B-load.
//    launch_bounds(256,2) -> VGPR cap 256, ~150 needed, no spill.
//  - Grid 512 (=2 blocks/CU): per-CU ds_read count halves 8192->4096
//    (the dominant pipe, ~98k -> ~49k cyc).
//  - Loss: vrow = Sz(row,fp64) + bestv; bv2a/bvfa store the same vrow so
//    fixup deltas cancel exactly (r11's fix, kept).
//
// d_out scratch (bytes, all consumed before small_gather / overwritten later):
//   [0,524288) cbh_perm | [524288,786432) bv2a | [786432,1048576) bvfa
//   [1048576,1572864) ull minkey scratch | [1572864,1835008) flagf
// d_ws: [0,2048) double loss_slots[256]; [2048,2052) cnt2; [2052,2056) cntf;
//       [4096,8192) float Bf[1024]; [8192,270336) uint flag2 (n | seck<<16)

#define N_PTS    65536
#define K_CODES  1024
#define DIM      256
#define MARGIN   1.5e-4f
#define WSKIP    4096

#define OUT_VALS  16777216
#define OUT_CODES 65536

typedef __attribute__((ext_vector_type(8))) short short8v;
typedef __attribute__((ext_vector_type(8))) _Float16 half8v;
typedef __attribute__((ext_vector_type(4))) float float4v;

// perm index (in shorts) for codebook element (r=code, k=dim):
// chunk = ((r>>4)*8 + (k>>5))*4 + ((k>>3)&3); idx = chunk*128 + (r&15)*8 + (k&7)
__device__ __forceinline__ int perm_idx(int r, int k) {
  return ((((r >> 4) * 8 + (k >> 5)) * 4 + ((k >> 3) & 3)) * 128) + (r & 15) * 8 + (k & 7);
}

__device__ __forceinline__ short f2h_bits(float x) {
  union { _Float16 h; short s; } u;
  u.h = (_Float16)x;              // v_cvt_f16_f32, RTE
  return u.s;
}

__device__ __forceinline__ void gload16(const void* g, void* l) {
  __builtin_amdgcn_global_load_lds(
      (const __attribute__((address_space(1))) unsigned*)g,
      (__attribute__((address_space(3))) unsigned*)l, 16, 0, 0);
}

// one wave per code row: Bf[r] = fl32(fp64 sum sq of ORIGINAL cb); emit
// fp16(1024*cb) in B-fragment-permuted order. Also init ws header + scratch.
__global__ void prep_cb_kernel(const float* __restrict__ cb,
                               short* __restrict__ cbh_perm,
                               float* __restrict__ Bf,
                               unsigned long long* __restrict__ scratch,
                               unsigned long long* __restrict__ ws0) {
  const int gid = blockIdx.x * 256 + threadIdx.x;
  scratch[gid] = ~0ull;                       // 65536 minkeys
  if (gid < 512) ws0[gid] = 0ull;             // loss_slots + cnt2/cntf
  int r    = blockIdx.x * 4 + (threadIdx.x >> 6);
  int lane = threadIdx.x & 63;
  const float4 v = *(const float4*)(cb + (size_t)r * DIM + lane * 4);
  double s = (double)v.x * v.x + (double)v.y * v.y
           + (double)v.z * v.z + (double)v.w * v.w;
#pragma unroll
  for (int off = 32; off > 0; off >>= 1) s += __shfl_down(s, off);
  if (lane == 0) Bf[r] = (float)s;
  short4 h = make_short4(f2h_bits(v.x * 1024.0f), f2h_bits(v.y * 1024.0f),
                         f2h_bits(v.z * 1024.0f), f2h_bits(v.w * 1024.0f));
  *(short4*)(cbh_perm + perm_idx(r, lane * 4)) = h;   // 8B aligned
}

// 512 blocks x 256 thr (4 waves). Block: 128 points x all 1024 codes.
// Wave w: 32 points (two 16-row A-groups). 32-code tiles double-buffered in
// LDS via global_load_lds; one barrier per tile; B-loads shared by both accs.
__global__ __launch_bounds__(256, 2) void argmin_mfma_kernel(
    const float* __restrict__ z, const float* __restrict__ cb,
    const short* __restrict__ cbh_perm,
    const float* __restrict__ Bf, float* __restrict__ outq,
    float* __restrict__ codes_out,
    int* __restrict__ cnt2, int* __restrict__ cntf,
    unsigned* __restrict__ flag2, int* __restrict__ flagf,
    float* __restrict__ bv2a, float* __restrict__ bvfa,
    double* __restrict__ loss_slots) {
  __shared__ __align__(16) short lbuf[2][8192];   // 2 x 16 KB (32 codes x 256d)
  __shared__ double wls[4];
  const int t    = threadIdx.x;
  const int w    = t >> 6;
  const int l    = t & 63;
  const int quad = l >> 4;
  const int lr   = l & 15;
  const int m0   = blockIdx.x * 128;
  const int pbase = m0 + w * 32;

  // stage tile 0 early (hides under A-load/convert)
  {
    const char* src = (const char*)cbh_perm;
    char* dst = (char*)&lbuf[0][0];
#pragma unroll
    for (int i = 0; i < 4; ++i)
      gload16(src + t * 16 + i * 4096, dst + t * 16 + i * 4096);
  }

  // A-fragments for 2 x 16 rows + fp64 row sums of squares.
  half8v ah[2][8];
  float Szrow[2];
#pragma unroll
  for (int a = 0; a < 2; ++a) {
    const float* zrow = z + (size_t)(pbase + a * 16 + lr) * DIM;
    double zs = 0.0;
#pragma unroll
    for (int q = 0; q < 8; ++q) {
      float4 p0 = *(const float4*)(zrow + q * 32 + quad * 8);
      float4 p1 = *(const float4*)(zrow + q * 32 + quad * 8 + 4);
      zs = fma((double)p0.x, (double)p0.x, zs);
      zs = fma((double)p0.y, (double)p0.y, zs);
      zs = fma((double)p0.z, (double)p0.z, zs);
      zs = fma((double)p0.w, (double)p0.w, zs);
      zs = fma((double)p1.x, (double)p1.x, zs);
      zs = fma((double)p1.y, (double)p1.y, zs);
      zs = fma((double)p1.z, (double)p1.z, zs);
      zs = fma((double)p1.w, (double)p1.w, zs);
      half8v hh;
      hh[0] = (_Float16)p0.x; hh[1] = (_Float16)p0.y;
      hh[2] = (_Float16)p0.z; hh[3] = (_Float16)p0.w;
      hh[4] = (_Float16)p1.x; hh[5] = (_Float16)p1.y;
      hh[6] = (_Float16)p1.z; hh[7] = (_Float16)p1.w;
      ah[a][q] = hh;
    }
    zs += __shfl_xor(zs, 16);      // sum the 4 quad partials, fixed lr
    zs += __shfl_xor(zs, 32);
    Szrow[a] = (float)zs;          // lane l: ||z[pbase + a*16 + (l&15)]||^2
  }

  // top-3 per slot s = a*4 + r  (row = a*16 + quad*4 + r)
  float bv[8], sv[8], tv[8]; int bk[8], sk[8];
#pragma unroll
  for (int s = 0; s < 8; ++s) {
    bv[s] = 3.0e38f; sv[s] = 3.0e38f; tv[s] = 3.0e38f; bk[s] = 0; sk[s] = 0;
  }

  __syncthreads();          // tile 0 resident (barrier drains vmcnt)
  int cur = 0;
  for (int it = 0; it < 32; ++it) {
    if (it < 31) {          // prefetch tile it+1 into the other buffer
      const char* src = (const char*)cbh_perm + (size_t)(it + 1) * 16384;
      char* dst = (char*)&lbuf[cur ^ 1][0];
#pragma unroll
      for (int i = 0; i < 4; ++i)
        gload16(src + t * 16 + i * 4096, dst + t * 16 + i * 4096);
    }
    const int c0 = it * 32;
#pragma unroll
    for (int st = 0; st < 2; ++st) {
      float4v acc0 = {0.f, 0.f, 0.f, 0.f};
      float4v acc1 = {0.f, 0.f, 0.f, 0.f};
#pragma unroll
      for (int q = 0; q < 8; ++q) {
        half8v b = *(const half8v*)(&lbuf[cur][(st * 8 + q) * 512 + quad * 128 + lr * 8]);
        acc0 = __builtin_amdgcn_mfma_f32_16x16x32_f16(ah[0][q], b, acc0, 0, 0, 0);
        acc1 = __builtin_amdgcn_mfma_f32_16x16x32_f16(ah[1][q], b, acc1, 0, 0, 0);
      }
      const int k = c0 + st * 16 + lr;       // this lane's code (C col = lr)
      const float bkf = Bf[k];
#pragma unroll
      for (int a = 0; a < 2; ++a) {
#pragma unroll
        for (int r = 0; r < 4; ++r) {
          const int s = a * 4 + r;
          float v = fmaf(-0.001953125f, a ? acc1[r] : acc0[r], bkf);  // -2/1024
          bool lt1 = v < bv[s];
          bool lt2 = v < sv[s];
          tv[s] = fminf(fmaxf(v, sv[s]), tv[s]);   // med3
          sv[s] = fminf(fmaxf(v, bv[s]), sv[s]);   // med3
          bv[s] = fminf(v, bv[s]);
          sk[s] = lt1 ? bk[s] : (lt2 ? k : sk[s]);
          bk[s] = lt1 ? k : bk[s];
        }
      }
    }
    __syncthreads();        // next tile landed; all readers done with cur
    cur ^= 1;
  }

  // top-3 merge across the 16 col-lanes of each quad (butterfly)
#pragma unroll
  for (int mask = 1; mask < 16; mask <<= 1) {
#pragma unroll
    for (int s = 0; s < 8; ++s) {
      float ov  = __shfl_xor(bv[s], mask);
      float os  = __shfl_xor(sv[s], mask);
      float ot  = __shfl_xor(tv[s], mask);
      int   ok  = __shfl_xor(bk[s], mask);
      int   osk = __shfl_xor(sk[s], mask);
      bool win = (ov < bv[s]) || (ov == bv[s] && ok < bk[s]);
      float a1 = win ? ov : bv[s], a2 = win ? os : sv[s], a3 = win ? ot : tv[s];
      int   a1k = win ? ok : bk[s], a2k = win ? osk : sk[s];
      float b1 = win ? bv[s] : ov, b2 = win ? sv[s] : os;
      int   b1k = win ? bk[s] : ok;
      bool s2 = (a2 < b1) || (a2 == b1 && a2k < b1k);
      bv[s] = a1; bk[s] = a1k;
      sv[s] = s2 ? a2 : b1; sk[s] = s2 ? a2k : b1k;
      tv[s] = s2 ? fminf(a3, b1) : fminf(a2, b2);
    }
  }

  // per-slot row loss values (all lanes active: shfl outside divergence)
  float vrow[8];
#pragma unroll
  for (int a = 0; a < 2; ++a)
#pragma unroll
    for (int r = 0; r < 4; ++r)
      vrow[a * 4 + r] = __shfl(Szrow[a], quad * 4 + r) + bv[a * 4 + r];

  // fused quantized scatter: 32 rows per wave (deferred if block < WSKIP)
  if (m0 >= WSKIP) {
#pragma unroll
    for (int p = 0; p < 32; ++p) {
      int c = __shfl(bk[(p >> 4) * 4 + (p & 3)], ((p >> 2) & 3) << 4);
      int n = pbase + p;
      *(float4*)(outq + (size_t)n * DIM + l * 4) =
          *(const float4*)(cb + (size_t)c * DIM + l * 4);
    }
  }

  // fused loss + codes + flags
  double ls = 0.0;
  if (lr == 0) {
#pragma unroll
    for (int s = 0; s < 8; ++s) ls += (double)vrow[s];
  }
  ls += __shfl_down(ls, 16);
  ls += __shfl_down(ls, 32);
  if (l == 0) wls[w] = ls;

  if (lr == 0) {
#pragma unroll
    for (int a = 0; a < 2; ++a)
#pragma unroll
      for (int r = 0; r < 4; ++r) {
        const int s = a * 4 + r;
        int n = pbase + a * 16 + quad * 4 + r;
        codes_out[n] = (float)bk[s];
        if (tv[s] - bv[s] < MARGIN) {
          int pos = atomicAdd(cntf, 1);
          flagf[pos] = n; bvfa[pos] = vrow[s];
        } else if (sv[s] - bv[s] < MARGIN) {
          int pos = atomicAdd(cnt2, 1);
          flag2[pos] = (unsigned)n | ((unsigned)sk[s] << 16);
          bv2a[pos] = vrow[s];
        }
      }
  }
  __syncthreads();
  if (t == 0)
    atomicAdd(&loss_slots[blockIdx.x & 255], wls[0] + wls[1] + wls[2] + wls[3]);
}

// Pair fixup: one wave per flagged row; half-wave per candidate code.
// Exact emulation: v = fl32(fl32(Sfl + Bf[k]) - 2*fl32(dot64)); tie -> lower k.
// Loss delta = v_exact(min) - bv2a[i] (bv2a = Sz + approx bv, the value added).
__global__ __launch_bounds__(256) void fixup_pair_kernel(
    const float* __restrict__ z, const float* __restrict__ cb,
    const float* __restrict__ Bf, const unsigned* __restrict__ flag2,
    const int* __restrict__ cnt2, const float* __restrict__ bv2a,
    float* __restrict__ codes_out, float* __restrict__ outq,
    double* __restrict__ loss_slots) {
  const int t   = threadIdx.x;
  const int l   = t & 63;
  const int h   = l >> 5;          // 0 -> bestk, 1 -> seck
  const int sub = l & 31;          // dims sub*8 .. sub*8+7
  const int wid = blockIdx.x * 4 + (t >> 6);
  const int nw  = gridDim.x * 4;
  const int cnt = *cnt2;
  for (int i = wid; i < cnt; i += nw) {
    const unsigned rec = flag2[i];
    const int n  = rec & 0xFFFF;
    const int k2 = rec >> 16;
    const int k1 = (int)codes_out[n];
    const int k  = h ? k2 : k1;
    const float* zr = z + (size_t)n * DIM + sub * 8;
    const float* cr = cb + (size_t)k * DIM + sub * 8;
    const float4 za = *(const float4*)(zr);
    const float4 zb = *(const float4*)(zr + 4);
    const float4 ca = *(const float4*)(cr);
    const float4 cv = *(const float4*)(cr + 4);
    double s = (double)za.x*za.x + (double)za.y*za.y + (double)za.z*za.z + (double)za.w*za.w
             + (double)zb.x*zb.x + (double)zb.y*zb.y + (double)zb.z*zb.z + (double)zb.w*zb.w;
    double d = (double)za.x*ca.x + (double)za.y*ca.y + (double)za.z*ca.z + (double)za.w*ca.w
             + (double)zb.x*cv.x + (double)zb.y*cv.y + (double)zb.z*cv.z + (double)zb.w*cv.w;
#pragma unroll
    for (int m = 1; m < 32; m <<= 1) {
      s += __shfl_xor(s, m);
      d += __shfl_xor(d, m);
    }
    const float Sfl = (float)s;
    const float T1  = Sfl + Bf[k];
    const float v   = T1 - 2.0f * (float)d;
    const float vo  = __shfl_xor(v, 32);
    const int   ko  = __shfl_xor(k, 32);
    const bool keep = (v < vo) || (v == vo && k < ko);
    const float vmin = keep ? v : vo;
    const int   kf   = keep ? k : ko;       // consistent across both halves
    if (l == 0) {
      codes_out[n] = (float)kf;
      atomicAdd(&loss_slots[n & 255], (double)(vmin - bv2a[i]));
    }
    if (kf != k1 && n >= WSKIP)
      *(float4*)(outq + (size_t)n * DIM + l * 4) =
          *(const float4*)(cb + (size_t)kf * DIM + l * 4);
  }
}

// Full rescan for rows with 3+ candidates inside MARGIN (expected ~tens).
// 4 blocks per row; cross-block merge via atomicMin on (f32-bits<<32 | k).
__global__ __launch_bounds__(256) void fixup_full_kernel(
    const float* __restrict__ z, const float* __restrict__ cb,
    const float* __restrict__ Bf, const int* __restrict__ flagf,
    const int* __restrict__ cntf, unsigned long long* __restrict__ scratch) {
  __shared__ float vred[4];
  __shared__ int   kred[4];
  const int t = threadIdx.x;
  const int w = t >> 6;
  const int l = t & 63;
  const int cnt = *cntf;
  for (int ib = blockIdx.x; (ib >> 2) < cnt; ib += gridDim.x) {
    const int i = ib >> 2, q = ib & 3;
    const int n = flagf[i];
    const float4 zv = *(const float4*)(z + (size_t)n * DIM + l * 4);
    double s = (double)zv.x*zv.x + (double)zv.y*zv.y
             + (double)zv.z*zv.z + (double)zv.w*zv.w;
#pragma unroll
    for (int off = 32; off > 0; off >>= 1) s += __shfl_xor(s, off);
    const float Sfl = (float)s;
    float bvv = 3.0e38f; int bkk = 0;
    const int kbase = q * 256 + w * 64;
#pragma unroll 4
    for (int k0 = 0; k0 < 64; ++k0) {
      const int k = kbase + k0;
      const float4 cv = *(const float4*)(cb + (size_t)k * DIM + l * 4);
      double d = (double)zv.x*cv.x + (double)zv.y*cv.y
               + (double)zv.z*cv.z + (double)zv.w*cv.w;
#pragma unroll
      for (int off = 32; off > 0; off >>= 1) d += __shfl_xor(d, off);
      float T1 = Sfl + Bf[k];
      float v  = T1 - 2.0f * (float)d;
      if (v < bvv) { bvv = v; bkk = k; }   // ascending k -> lowest on tie
    }
    __syncthreads();
    if (l == 0) { vred[w] = bvv; kred[w] = bkk; }
    __syncthreads();
    if (t == 0) {
      float fv = vred[0]; int fk = kred[0];
#pragma unroll
      for (int j = 1; j < 4; ++j) {
        float v2 = vred[j]; int kk = kred[j];
        if (v2 < fv || (v2 == fv && kk < fk)) { fv = v2; fk = kk; }
      }
      unsigned long long key =
          ((unsigned long long)__float_as_uint(fv) << 32) | (unsigned)fk;
      atomicMin(&scratch[n], key);
    }
  }
}

// Resolve full rows: wave per row; codes + loss delta + row rewrite.
__global__ __launch_bounds__(256) void fixup_write_kernel(
    const int* __restrict__ flagf, const int* __restrict__ cntf,
    const unsigned long long* __restrict__ scratch,
    const float* __restrict__ bvfa, const float* __restrict__ cb,
    float* __restrict__ codes_out, float* __restrict__ outq,
    double* __restrict__ loss_slots) {
  const int t = threadIdx.x, l = t & 63;
  const int wid = blockIdx.x * 4 + (t >> 6);
  const int nw  = gridDim.x * 4;
  const int cnt = *cntf;
  for (int i = wid; i < cnt; i += nw) {
    const int n = flagf[i];
    const unsigned long long key = scratch[n];
    const int   fk = (int)(unsigned)(key & 0xFFFFFFFFull);
    const float fv = __uint_as_float((unsigned)(key >> 32));
    const int   k1 = (int)codes_out[n];
    if (l == 0) {
      codes_out[n] = (float)fk;
      atomicAdd(&loss_slots[n & 255], (double)(fv - bvfa[i]));
    }
    if (fk != k1 && n >= WSKIP)
      *(float4*)(outq + (size_t)n * DIM + l * 4) =
          *(const float4*)(cb + (size_t)fk * DIM + l * 4);
  }
}

// Rows [0, WSKIP): scatter cb[codes[n]] after all fixups (scratch now dead).
__global__ void small_gather_kernel(const float* __restrict__ cb,
                                    const float* __restrict__ codes_f,
                                    float* __restrict__ outq) {
  int gid = blockIdx.x * 256 + threadIdx.x;
  int n = gid >> 6, l = gid & 63;
  int c = (int)codes_f[n];
  *(float4*)(outq + (size_t)n * DIM + l * 4) =
      *(const float4*)(cb + (size_t)c * DIM + l * 4);
}

__global__ void finalize_kernel(const double* __restrict__ loss_slots,
                                float* __restrict__ out_loss) {
  const int t = threadIdx.x;          // 256 threads
  double s = loss_slots[t];
#pragma unroll
  for (int off = 32; off > 0; off >>= 1) s += __shfl_down(s, off);
  __shared__ double ws[4];
  if ((t & 63) == 0) ws[t >> 6] = s;
  __syncthreads();
  if (t == 0) {
    double tot = ws[0] + ws[1] + ws[2] + ws[3];
    out_loss[0] = (float)(1.25 * tot / (double)(N_PTS * (size_t)DIM));
  }
}

extern "C" void kernel_launch(void* const* d_in, const int* in_sizes, int n_in,
                              void* d_out, int out_size, void* d_ws, size_t ws_size,
                              hipStream_t stream) {
  const float* z  = (const float*)d_in[0];
  const float* cb = (const float*)d_in[1];
  float* out = (float*)d_out;
  double* loss_slots = (double*)d_ws;
  int*      cnt2  = (int*)((char*)d_ws + 2048);
  int*      cntf  = (int*)((char*)d_ws + 2052);
  float*    Bf    = (float*)((char*)d_ws + 4096);
  unsigned* flag2 = (unsigned*)((char*)d_ws + 8192);
  short* cbh_perm = (short*)d_out;                                   // [0,512K)
  float* bv2a     = (float*)((char*)d_out + 524288);
  float* bvfa     = (float*)((char*)d_out + 786432);
  unsigned long long* scratch = (unsigned long long*)((char*)d_out + 1048576);
  int*   flagf    = (int*)((char*)d_out + 1572864);

  prep_cb_kernel<<<K_CODES / 4, 256, 0, stream>>>(
      cb, cbh_perm, Bf, scratch, (unsigned long long*)d_ws);
  argmin_mfma_kernel<<<N_PTS / 128, 256, 0, stream>>>(
      z, cb, cbh_perm, Bf, out, out + OUT_VALS, cnt2, cntf, flag2, flagf,
      bv2a, bvfa, loss_slots);
  fixup_pair_kernel<<<1024, 256, 0, stream>>>(
      z, cb, Bf, flag2, cnt2, bv2a, out + OUT_VALS, out, loss_slots);
  fixup_full_kernel<<<2048, 256, 0, stream>>>(z, cb, Bf, flagf, cntf, scratch);
  fixup_write_kernel<<<64, 256, 0, stream>>>(
      flagf, cntf, scratch, bvfa, cb, out + OUT_VALS, out, loss_slots);
  small_gather_kernel<<<WSKIP * 64 / 256, 256, 0, stream>>>(
      cb, out + OUT_VALS, out);
  finalize_kernel<<<1, 256, 0, stream>>>(loss_slots, out + OUT_VALS + OUT_CODES);
}